// Round 2
// baseline (456.655 us; speedup 1.0000x reference)
//
#include <hip/hip_runtime.h>
#include <hip/hip_bf16.h>

typedef __bf16 bf16;
typedef __attribute__((ext_vector_type(8))) __bf16 bf16x8;
typedef __attribute__((ext_vector_type(4))) __bf16 bf16x4;
typedef __attribute__((ext_vector_type(4))) float f32x4;

#define MFMA_BF16 __builtin_amdgcn_mfma_f32_16x16x32_bf16

// Problem constants
static constexpr int NB = 4;      // batches
static constexpr int NN = 8192;   // sequence length
static constexpr int DM = 1024;   // d_model
static constexpr int DK = 128;    // d_k
// rows total = NB*NN = 32768

// ---------------------------------------------------------------------------
// Kernel 0: zero the fp32 M accumulator; convert Wq/Wk fp32 -> bf16.
// grid 512 x 256 = 131072 threads.
// ---------------------------------------------------------------------------
__global__ __launch_bounds__(256) void k_prep(const float* __restrict__ Wq,
                                              const float* __restrict__ Wk,
                                              float* __restrict__ Mtf,
                                              bf16* __restrict__ Wqb,
                                              bf16* __restrict__ Wkb) {
  const int i = blockIdx.x * 256 + threadIdx.x;  // 0..131071
#pragma unroll
  for (int t = 0; t < 4; ++t) Mtf[i + t * 131072] = 0.0f;  // 524288 total
  Wqb[i] = (bf16)Wq[i];
  Wkb[i] = (bf16)Wk[i];
}

// ---------------------------------------------------------------------------
// Kernel 1: Q = J @ Wq^T (row-major bf16), Kt = (J @ Wk^T)^T (k-major bf16)
// block = 256 thr (4 waves), each wave: 16 rows x 128 outs for Q and K.
// J is fp32, converted to bf16 in-register.
// ---------------------------------------------------------------------------
__global__ __launch_bounds__(256) void k_qk(const float* __restrict__ J,
                                            const bf16* __restrict__ Wqb,
                                            const bf16* __restrict__ Wkb,
                                            bf16* __restrict__ Q,
                                            bf16* __restrict__ Kt) {
  const int wave = threadIdx.x >> 6;
  const int lane = threadIdx.x & 63;
  const int l16 = lane & 15, quad = lane >> 4;
  const int rbase = blockIdx.x * 64 + wave * 16;

  f32x4 accq[8] = {};
  f32x4 acck[8] = {};

  const float* jrow = J + (size_t)(rbase + l16) * DM + quad * 8;
  for (int d = 0; d < DM; d += 32) {
    f32x4 j0 = *(const f32x4*)(jrow + d);
    f32x4 j1 = *(const f32x4*)(jrow + d + 4);
    bf16x8 a;
#pragma unroll
    for (int t = 0; t < 4; ++t) {
      a[t] = (bf16)j0[t];
      a[t + 4] = (bf16)j1[t];
    }
#pragma unroll
    for (int t = 0; t < 8; ++t) {
      bf16x8 bq = *(const bf16x8*)(Wqb + (size_t)(t * 16 + l16) * DM + d + quad * 8);
      accq[t] = MFMA_BF16(a, bq, accq[t], 0, 0, 0);
    }
#pragma unroll
    for (int t = 0; t < 8; ++t) {
      bf16x8 bk = *(const bf16x8*)(Wkb + (size_t)(t * 16 + l16) * DM + d + quad * 8);
      acck[t] = MFMA_BF16(a, bk, acck[t], 0, 0, 0);
    }
  }

  // Q write: row = rbase + quad*4 + r, col = t*16 + l16  (row-major)
  const int row0 = rbase + quad * 4;
#pragma unroll
  for (int t = 0; t < 8; ++t) {
    const int col = t * 16 + l16;
#pragma unroll
    for (int r = 0; r < 4; ++r)
      Q[(size_t)(row0 + r) * DK + col] = (bf16)accq[t][r];
  }

  // Kt write: Kt[b][k][n], 4 consecutive n per lane -> packed 8B store
  const int b = rbase >> 13;            // rbase / 8192
  const int nloc = (rbase & (NN - 1)) + quad * 4;
#pragma unroll
  for (int t = 0; t < 8; ++t) {
    const int k = t * 16 + l16;
    bf16x4 pv;
#pragma unroll
    for (int r = 0; r < 4; ++r) pv[r] = (bf16)acck[t][r];
    *(bf16x4*)(Kt + (size_t)(b * DK + k) * NN + nloc) = pv;
  }
}

// ---------------------------------------------------------------------------
// Kernel 2: Mt[b][d][k] += sum_n J[b][n][d] * K[b][n][k]   (fp32 atomics)
// grid: 4 batch x 8 d-chunk(128) x 16 n-split(512) = 512 blocks.
// A-frag (J^T, fp32) via strided scalar loads + cvt; B-frag (Kt bf16) 16B loads.
// ---------------------------------------------------------------------------
__global__ __launch_bounds__(256) void k_m(const float* __restrict__ J,
                                           const bf16* __restrict__ Kt,
                                           float* __restrict__ Mt) {
  const int bid = blockIdx.x;
  const int b = bid & 3;
  const int dchunk = (bid >> 2) & 7;
  const int nsplit = bid >> 5;  // 0..15
  const int wave = threadIdx.x >> 6, lane = threadIdx.x & 63;
  const int l16 = lane & 15, quad = lane >> 4;
  const int dbase = dchunk * 128 + wave * 32;

  const float* Jb = J + (size_t)b * NN * DM;
  const bf16* Ktb = Kt + (size_t)b * DK * NN;

  f32x4 acc[2][8] = {};

  for (int ns = 0; ns < 512; ns += 32) {
    const int n0 = nsplit * 512 + ns + quad * 8;
    bf16x8 aj[2];
#pragma unroll
    for (int dt = 0; dt < 2; ++dt) {
      const int d = dbase + dt * 16 + l16;
      const float* p = Jb + (size_t)n0 * DM + d;
#pragma unroll
      for (int j = 0; j < 8; ++j) aj[dt][j] = (bf16)p[(size_t)j * DM];
    }
#pragma unroll
    for (int kt = 0; kt < 8; ++kt) {
      bf16x8 bk = *(const bf16x8*)(Ktb + (size_t)(kt * 16 + l16) * NN + n0);
      acc[0][kt] = MFMA_BF16(aj[0], bk, acc[0][kt], 0, 0, 0);
      acc[1][kt] = MFMA_BF16(aj[1], bk, acc[1][kt], 0, 0, 0);
    }
  }

#pragma unroll
  for (int dt = 0; dt < 2; ++dt) {
    const int d = dbase + dt * 16 + quad * 4;
#pragma unroll
    for (int kt = 0; kt < 8; ++kt) {
      const int k = kt * 16 + l16;
#pragma unroll
      for (int r = 0; r < 4; ++r)
        atomicAdd(&Mt[((size_t)b * DM + d + r) * DK + k], acc[dt][kt][r]);
    }
  }
}

// ---------------------------------------------------------------------------
// Kernel 2b: Mt fp32 -> bf16 with 1/sqrt(128) folded in.
// ---------------------------------------------------------------------------
__global__ __launch_bounds__(256) void k_cvt(const float* __restrict__ Mt,
                                             bf16* __restrict__ Mtb) {
  const float s = 0.08838834764831845f;  // 1/sqrt(128)
  const int total = NB * DM * DK;        // 524288
  for (int i = blockIdx.x * 256 + threadIdx.x; i < total; i += 512 * 256)
    Mtb[i] = (bf16)(Mt[i] * s);
}

// ---------------------------------------------------------------------------
// Kernel 3: out = LN(Q @ M + J) * gamma + beta   (1/sqrt(dk) folded in Mtb)
// block = 256 thr (4 waves), 32 rows x 1024 cols; each wave 32 rows x 256 cols.
// J residual / gamma / beta / out are fp32.
// ---------------------------------------------------------------------------
__global__ __launch_bounds__(256) void k_out(const float* __restrict__ J,
                                             const bf16* __restrict__ Q,
                                             const bf16* __restrict__ Mtb,
                                             const float* __restrict__ gamma,
                                             const float* __restrict__ beta,
                                             float* __restrict__ out) {
  __shared__ float S[4][32][2];
  const int wave = threadIdx.x >> 6, lane = threadIdx.x & 63;
  const int l16 = lane & 15, quad = lane >> 4;
  const int rbase = blockIdx.x * 32;
  const int b = rbase >> 13;
  const int cbase = wave * 256;
  const bf16* M = Mtb + (size_t)b * DM * DK;

  f32x4 acc[2][16] = {};

#pragma unroll
  for (int ks = 0; ks < DK; ks += 32) {
    bf16x8 aq[2];
#pragma unroll
    for (int rt = 0; rt < 2; ++rt)
      aq[rt] = *(const bf16x8*)(Q + (size_t)(rbase + rt * 16 + l16) * DK + ks + quad * 8);
#pragma unroll
    for (int ct = 0; ct < 16; ++ct) {
      bf16x8 bm = *(const bf16x8*)(M + (size_t)(cbase + ct * 16 + l16) * DK + ks + quad * 8);
      acc[0][ct] = MFMA_BF16(aq[0], bm, acc[0][ct], 0, 0, 0);
      acc[1][ct] = MFMA_BF16(aq[1], bm, acc[1][ct], 0, 0, 0);
    }
  }

  // add J (fp32), accumulate row partial sums (this wave: 256 of 1024 cols)
  float s1[2][4] = {}, s2[2][4] = {};
#pragma unroll
  for (int rt = 0; rt < 2; ++rt) {
    const int row = rbase + rt * 16 + quad * 4;
#pragma unroll
    for (int ct = 0; ct < 16; ++ct) {
      const int col = cbase + ct * 16 + l16;
      const float* jp = J + (size_t)row * DM + col;
#pragma unroll
      for (int r = 0; r < 4; ++r) {
        float x = acc[rt][ct][r] + jp[(size_t)r * DM];
        acc[rt][ct][r] = x;
        s1[rt][r] += x;
        s2[rt][r] += x * x;
      }
    }
  }
  // reduce across the 16 lanes of each quad (cols)
#pragma unroll
  for (int off = 1; off < 16; off <<= 1) {
#pragma unroll
    for (int rt = 0; rt < 2; ++rt)
#pragma unroll
      for (int r = 0; r < 4; ++r) {
        s1[rt][r] += __shfl_xor(s1[rt][r], off);
        s2[rt][r] += __shfl_xor(s2[rt][r], off);
      }
  }
  if (l16 == 0) {
#pragma unroll
    for (int rt = 0; rt < 2; ++rt)
#pragma unroll
      for (int r = 0; r < 4; ++r) {
        const int lrow = rt * 16 + quad * 4 + r;
        S[wave][lrow][0] = s1[rt][r];
        S[wave][lrow][1] = s2[rt][r];
      }
  }
  __syncthreads();

  float mu[2][4], inv[2][4];
#pragma unroll
  for (int rt = 0; rt < 2; ++rt)
#pragma unroll
    for (int r = 0; r < 4; ++r) {
      const int lrow = rt * 16 + quad * 4 + r;
      float a1 = S[0][lrow][0] + S[1][lrow][0] + S[2][lrow][0] + S[3][lrow][0];
      float a2 = S[0][lrow][1] + S[1][lrow][1] + S[2][lrow][1] + S[3][lrow][1];
      float m = a1 * (1.0f / DM);
      float v = a2 * (1.0f / DM) - m * m;
      mu[rt][r] = m;
      inv[rt][r] = rsqrtf(v + 1e-5f);
    }

#pragma unroll
  for (int rt = 0; rt < 2; ++rt) {
    const int row = rbase + rt * 16 + quad * 4;
#pragma unroll
    for (int ct = 0; ct < 16; ++ct) {
      const int col = cbase + ct * 16 + l16;
      const float g = gamma[col];
      const float be = beta[col];
#pragma unroll
      for (int r = 0; r < 4; ++r) {
        float y = (acc[rt][ct][r] - mu[rt][r]) * inv[rt][r] * g + be;
        out[(size_t)(row + r) * DM + col] = y;
      }
    }
  }
}

// ---------------------------------------------------------------------------
// launch
// ---------------------------------------------------------------------------
extern "C" void kernel_launch(void* const* d_in, const int* in_sizes, int n_in,
                              void* d_out, int out_size, void* d_ws, size_t ws_size,
                              hipStream_t stream) {
  const float* J = (const float*)d_in[0];
  const float* Wq = (const float*)d_in[1];
  const float* Wk = (const float*)d_in[2];
  const float* gamma = (const float*)d_in[3];
  const float* beta = (const float*)d_in[4];
  float* out = (float*)d_out;

  // workspace layout (bytes):
  //   [0,        2 MiB)   Mt fp32   (4*1024*128*4)
  //   [2 MiB,    3 MiB)   Mt bf16   (4*1024*128*2)
  //   [3 MiB,   11 MiB)   Q  bf16   (32768*128*2)
  //   [11 MiB,  19 MiB)   Kt bf16   (4*128*8192*2)
  //   [19 MiB,  19.25)    Wq bf16   (128*1024*2)
  //   [19.25,   19.5)     Wk bf16   (128*1024*2)
  char* ws = (char*)d_ws;
  float* Mt_f = (float*)ws;
  bf16* Mt_b = (bf16*)(ws + ((size_t)2 << 20));
  bf16* Qw = (bf16*)(ws + ((size_t)3 << 20));
  bf16* Ktw = (bf16*)(ws + ((size_t)11 << 20));
  bf16* Wqb = (bf16*)(ws + ((size_t)19 << 20));
  bf16* Wkb = (bf16*)(ws + ((size_t)19 << 20) + (256u << 10));

  k_prep<<<512, 256, 0, stream>>>(Wq, Wk, Mt_f, Wqb, Wkb);
  k_qk<<<512, 256, 0, stream>>>(J, Wqb, Wkb, Qw, Ktw);
  k_m<<<512, 256, 0, stream>>>(J, Ktw, Mt_f);
  k_cvt<<<512, 256, 0, stream>>>(Mt_f, Mt_b);
  k_out<<<1024, 256, 0, stream>>>(J, Qw, Mt_b, gamma, beta, out);
}

// Round 3
// 383.849 us; speedup vs baseline: 1.1897x; 1.1897x over previous
//
#include <hip/hip_runtime.h>
#include <hip/hip_bf16.h>
#include <stdint.h>

typedef __bf16 bf16;
typedef __attribute__((ext_vector_type(8))) __bf16 bf16x8;
typedef __attribute__((ext_vector_type(4))) __bf16 bf16x4;
typedef __attribute__((ext_vector_type(4))) float f32x4;

#define MFMA_BF16 __builtin_amdgcn_mfma_f32_16x16x32_bf16

static constexpr int NB = 4;      // batches
static constexpr int NN = 8192;   // sequence length
static constexpr int DM = 1024;   // d_model
static constexpr int DK = 128;    // d_k

#define GLDS16(gp, lp)                                                              \
  __builtin_amdgcn_global_load_lds((const __attribute__((address_space(1))) void*)(gp), \
                                   (__attribute__((address_space(3))) void*)(lp), 16, 0, 0)

// ---------------------------------------------------------------------------
// Kernel 0: zero fp32 M accumulator; build merged Wb[256][1024] bf16
// (rows 0..127 = Wq, 128..255 = Wk).
// ---------------------------------------------------------------------------
__global__ __launch_bounds__(256) void k_prep(const float* __restrict__ Wq,
                                              const float* __restrict__ Wk,
                                              float* __restrict__ Mtf,
                                              bf16* __restrict__ Wb) {
  const int i = blockIdx.x * 256 + threadIdx.x;  // 0..131071
#pragma unroll
  for (int t2 = 0; t2 < 4; ++t2) Mtf[i + t2 * 131072] = 0.0f;  // 524288 total
  Wb[i] = (bf16)Wq[i];
  Wb[i + 131072] = (bf16)Wk[i];
}

// ---------------------------------------------------------------------------
// Kernel 1: Q = J @ Wq^T (row-major bf16), Kt = (J @ Wk^T)^T (k-major bf16)
// Block: 64 J-rows x 256 outputs (Q128|K128). glds-staged LDS, double-buffered,
// XOR-swizzled granules for conflict-free MFMA fragment reads.
// LDS: J 2x8KB [0,16K) ; W 2x16KB [16K,48K)
// ---------------------------------------------------------------------------
__global__ __launch_bounds__(256) void k_qk(const float* __restrict__ J,
                                            const bf16* __restrict__ Wb,
                                            bf16* __restrict__ Q,
                                            bf16* __restrict__ Kt) {
  __shared__ __align__(16) char lds[49152];
  const int t = threadIdx.x, w = t >> 6;
  const int l16 = t & 15, quad = (t >> 4) & 3;
  const int rbase = blockIdx.x * 64;

  f32x4 acc[16] = {};

  auto stage = [&](int c) {
    const int d0 = c * 32, buf = c & 1;
    // J tile: 64 rows x 8 granules (granule = 4 fp32 = 16B), swizzle sg = gc ^ (r&7)
#pragma unroll
    for (int i = 0; i < 2; ++i) {
      int s = i * 256 + t;
      int r = s >> 3, sg = s & 7;
      int gc = sg ^ (r & 7);
      const float* gp = J + (size_t)(rbase + r) * DM + d0 + gc * 4;
      int off = __builtin_amdgcn_readfirstlane(buf * 8192 + (i * 256 + w * 64) * 16);
      GLDS16(gp, lds + off);
    }
    // W tile: 256 rows x 4 granules (granule = 8 bf16 = 16B), swizzle sg = gc ^ ((r>>1)&3)
#pragma unroll
    for (int i = 0; i < 4; ++i) {
      int s = i * 256 + t;
      int r = s >> 2, sg = s & 3;
      int gc = sg ^ ((r >> 1) & 3);
      const bf16* gp = Wb + (size_t)r * DM + d0 + gc * 8;
      int off = __builtin_amdgcn_readfirstlane(16384 + buf * 16384 + (i * 256 + w * 64) * 16);
      GLDS16(gp, lds + off);
    }
  };

  stage(0);
  for (int c = 0; c < 32; ++c) {
    __syncthreads();              // drains own-wave glds (vmcnt) + joins waves
    if (c < 31) stage(c + 1);     // DMA of next chunk overlaps compute below
    const int buf = c & 1;
    // A-frag: row r = w*16+l16, fp32 granules (2*quad, 2*quad+1) swizzled
    const int r = w * 16 + l16;
    f32x4 ja = *(const f32x4*)(lds + buf * 8192 + ((r * 8 + ((2 * quad) ^ (r & 7))) * 16));
    f32x4 jb = *(const f32x4*)(lds + buf * 8192 + ((r * 8 + ((2 * quad + 1) ^ (r & 7))) * 16));
    bf16x8 a;
#pragma unroll
    for (int e = 0; e < 4; ++e) { a[e] = (bf16)ja[e]; a[4 + e] = (bf16)jb[e]; }
#pragma unroll
    for (int kt = 0; kt < 16; ++kt) {
      const int row = kt * 16 + l16;
      bf16x8 bfrag = *(const bf16x8*)(lds + 16384 + buf * 16384 +
                                      ((row * 4 + (quad ^ ((row >> 1) & 3))) * 16));
      acc[kt] = MFMA_BF16(a, bfrag, acc[kt], 0, 0, 0);
    }
  }

  // epilogue: Q row-major; Kt k-major (transposed via C-layout)
  const int row0 = rbase + w * 16 + quad * 4;
#pragma unroll
  for (int kt = 0; kt < 8; ++kt) {
    const int col = kt * 16 + l16;
#pragma unroll
    for (int r2 = 0; r2 < 4; ++r2)
      Q[(size_t)(row0 + r2) * DK + col] = (bf16)acc[kt][r2];
  }
  const int b = rbase >> 13;
  const int nloc = (rbase & (NN - 1)) + w * 16 + quad * 4;
#pragma unroll
  for (int kt = 0; kt < 8; ++kt) {
    const int k = kt * 16 + l16;
    bf16x4 pv;
#pragma unroll
    for (int r2 = 0; r2 < 4; ++r2) pv[r2] = (bf16)acc[8 + kt][r2];
    *(bf16x4*)(Kt + (size_t)(b * DK + k) * NN + nloc) = pv;
  }
}

// ---------------------------------------------------------------------------
// Kernel 2: Mt[b][d][k] += sum_n J[b][n][d] * K[b][n][k]  (fp32 atomics)
// grid 512 = 4b x 8 dchunk(128) x 16 nsplit(512). Per n-chunk(32): stage
// J[32n][128d] fp32 (16KB) + Kt[128k][32n] bf16 (8KB) via swizzled glds.
// A-frags (J^T) read transposed from LDS via paired b32 reads, conflict-free.
// LDS: J 2x16KB [0,32K) ; Kt 2x8KB [32K,48K)
// ---------------------------------------------------------------------------
__global__ __launch_bounds__(256) void k_m(const float* __restrict__ J,
                                           const bf16* __restrict__ Kt,
                                           float* __restrict__ Mt) {
  __shared__ __align__(16) char lds[49152];
  const int bid = blockIdx.x;
  const int b = bid & 3, dch = (bid >> 2) & 7, ns = bid >> 5;
  const int t = threadIdx.x, w = t >> 6;
  const int l16 = t & 15, quad = (t >> 4) & 3;
  const float* Jb = J + (size_t)b * NN * DM + (size_t)(ns * 512) * DM + dch * 128;
  const bf16* Ktb = Kt + (size_t)(b * DK) * NN + ns * 512;

  f32x4 acc[2][8] = {};

  auto stage = [&](int c) {
    const int buf = c & 1, n0 = c * 32;
    // J tile: 32 n x 32 granules (granule = 4 fp32), swizzle sg = gc ^ (2*((n>>3)&3))
#pragma unroll
    for (int i = 0; i < 4; ++i) {
      int s = i * 256 + t;
      int n = s >> 5, sg = s & 31;
      int gc = sg ^ (2 * ((n >> 3) & 3));
      const float* gp = Jb + (size_t)(n0 + n) * DM + gc * 4;
      int off = __builtin_amdgcn_readfirstlane(buf * 16384 + (i * 256 + w * 64) * 16);
      GLDS16(gp, lds + off);
    }
    // Kt tile: 128 k x 4 granules (granule = 8 bf16), swizzle sg = gc ^ ((k>>1)&3)
#pragma unroll
    for (int i = 0; i < 2; ++i) {
      int s = i * 256 + t;
      int k = s >> 2, sg = s & 3;
      int gc = sg ^ ((k >> 1) & 3);
      const bf16* gp = Ktb + (size_t)k * NN + n0 + gc * 8;
      int off = __builtin_amdgcn_readfirstlane(32768 + buf * 8192 + (i * 256 + w * 64) * 16);
      GLDS16(gp, lds + off);
    }
  };

  stage(0);
  for (int c = 0; c < 16; ++c) {
    __syncthreads();
    if (c < 15) stage(c + 1);
    const int buf = c & 1;
    // A-frags: af[dt][j] = (bf16)J[n=quad*8+j][d = w*32 + dt*16 + l16]
    bf16x8 af[2];
#pragma unroll
    for (int dt = 0; dt < 2; ++dt) {
      const int gc = w * 8 + dt * 4 + (l16 >> 2);   // fp32 granule col of d
      const int db = (l16 & 3) * 4;                 // dword offset inside granule
#pragma unroll
      for (int p = 0; p < 4; ++p) {
        const int n = quad * 8 + 2 * p;
        const int slot = n * 32 + (gc ^ (2 * quad));
        const char* base = lds + buf * 16384 + slot * 16 + db;
        float f0 = *(const float*)base;          // J[n][d]
        float f1 = *(const float*)(base + 512);  // J[n+1][d] (next row, same swizzle)
        af[dt][2 * p] = (bf16)f0;
        af[dt][2 * p + 1] = (bf16)f1;
      }
    }
#pragma unroll
    for (int kt = 0; kt < 8; ++kt) {
      const int k = kt * 16 + l16;
      bf16x8 bfrag = *(const bf16x8*)(lds + 32768 + buf * 8192 +
                                      ((k * 4 + (quad ^ ((k >> 1) & 3))) * 16));
      acc[0][kt] = MFMA_BF16(af[0], bfrag, acc[0][kt], 0, 0, 0);
      acc[1][kt] = MFMA_BF16(af[1], bfrag, acc[1][kt], 0, 0, 0);
    }
  }

#pragma unroll
  for (int dt = 0; dt < 2; ++dt) {
    const int d = dch * 128 + w * 32 + dt * 16 + quad * 4;
#pragma unroll
    for (int kt = 0; kt < 8; ++kt) {
      const int k = kt * 16 + l16;
#pragma unroll
      for (int r = 0; r < 4; ++r)
        atomicAdd(&Mt[(size_t)(b * DM + d + r) * DK + k], acc[dt][kt][r]);
    }
  }
}

// ---------------------------------------------------------------------------
// Kernel 2b: Mt fp32 -> bf16 with 1/sqrt(128) folded in.
// ---------------------------------------------------------------------------
__global__ __launch_bounds__(256) void k_cvt(const float* __restrict__ Mt,
                                             bf16* __restrict__ Mtb) {
  const float s = 0.08838834764831845f;  // 1/sqrt(128)
  const int total = NB * DM * DK;        // 524288
  for (int i = blockIdx.x * 256 + threadIdx.x; i < total; i += 512 * 256)
    Mtb[i] = (bf16)(Mt[i] * s);
}

// ---------------------------------------------------------------------------
// Kernel 3: out = LN(Q @ M + J) * gamma + beta  (1/sqrt(dk) folded in Mtb)
// 16 rows/block, 2048 blocks; each wave 16 rows x 256 cols (acc = 64 VGPR).
// ---------------------------------------------------------------------------
__global__ __launch_bounds__(256) void k_out(const float* __restrict__ J,
                                             const bf16* __restrict__ Q,
                                             const bf16* __restrict__ Mtb,
                                             const float* __restrict__ gamma,
                                             const float* __restrict__ beta,
                                             float* __restrict__ out) {
  __shared__ float S[4][16][2];
  const int t = threadIdx.x, w = t >> 6;
  const int l16 = t & 15, quad = (t >> 4) & 3;
  const int rbase = blockIdx.x * 16;
  const int b = rbase >> 13;
  const int cbase = w * 256;
  const bf16* M = Mtb + (size_t)b * DM * DK;

  f32x4 acc[16] = {};
#pragma unroll
  for (int ks = 0; ks < DK; ks += 32) {
    bf16x8 aq = *(const bf16x8*)(Q + (size_t)(rbase + l16) * DK + ks + quad * 8);
#pragma unroll
    for (int ct = 0; ct < 16; ++ct) {
      bf16x8 bm = *(const bf16x8*)(M + (size_t)(cbase + ct * 16 + l16) * DK + ks + quad * 8);
      acc[ct] = MFMA_BF16(aq, bm, acc[ct], 0, 0, 0);
    }
  }

  float s1[4] = {}, s2[4] = {};
  const int row = rbase + quad * 4;
#pragma unroll
  for (int ct = 0; ct < 16; ++ct) {
    const int col = cbase + ct * 16 + l16;
    const float* jp = J + (size_t)row * DM + col;
#pragma unroll
    for (int r = 0; r < 4; ++r) {
      float x = acc[ct][r] + jp[(size_t)r * DM];
      acc[ct][r] = x;
      s1[r] += x;
      s2[r] += x * x;
    }
  }
#pragma unroll
  for (int off = 1; off < 16; off <<= 1)
#pragma unroll
    for (int r = 0; r < 4; ++r) {
      s1[r] += __shfl_xor(s1[r], off);
      s2[r] += __shfl_xor(s2[r], off);
    }
  if (l16 == 0)
#pragma unroll
    for (int r = 0; r < 4; ++r) {
      S[w][quad * 4 + r][0] = s1[r];
      S[w][quad * 4 + r][1] = s2[r];
    }
  __syncthreads();

  float mu[4], inv[4];
#pragma unroll
  for (int r = 0; r < 4; ++r) {
    const int lr = quad * 4 + r;
    float a1 = S[0][lr][0] + S[1][lr][0] + S[2][lr][0] + S[3][lr][0];
    float a2 = S[0][lr][1] + S[1][lr][1] + S[2][lr][1] + S[3][lr][1];
    float m = a1 * (1.0f / DM);
    float v = a2 * (1.0f / DM) - m * m;
    mu[r] = m;
    inv[r] = rsqrtf(v + 1e-5f);
  }
#pragma unroll
  for (int ct = 0; ct < 16; ++ct) {
    const int col = cbase + ct * 16 + l16;
    const float g = gamma[col], be = beta[col];
#pragma unroll
    for (int r = 0; r < 4; ++r)
      out[(size_t)(row + r) * DM + col] = (acc[ct][r] - mu[r]) * inv[r] * g + be;
  }
}

// ---------------------------------------------------------------------------
// launch
// ---------------------------------------------------------------------------
extern "C" void kernel_launch(void* const* d_in, const int* in_sizes, int n_in,
                              void* d_out, int out_size, void* d_ws, size_t ws_size,
                              hipStream_t stream) {
  const float* J = (const float*)d_in[0];
  const float* Wq = (const float*)d_in[1];
  const float* Wk = (const float*)d_in[2];
  const float* gamma = (const float*)d_in[3];
  const float* beta = (const float*)d_in[4];
  float* out = (float*)d_out;

  // workspace: Mt_f fp32 [0,2M); Mt_b bf16 [2M,3M); Q bf16 [3M,11M);
  //            Kt bf16 [11M,19M); Wb bf16 [19M,19.5M)   (total 19.5 MiB)
  char* ws = (char*)d_ws;
  float* Mt_f = (float*)ws;
  bf16* Mt_b = (bf16*)(ws + ((size_t)2 << 20));
  bf16* Qw = (bf16*)(ws + ((size_t)3 << 20));
  bf16* Ktw = (bf16*)(ws + ((size_t)11 << 20));
  bf16* Wb = (bf16*)(ws + ((size_t)19 << 20));

  k_prep<<<512, 256, 0, stream>>>(Wq, Wk, Mt_f, Wb);
  k_qk<<<512, 256, 0, stream>>>(J, Wb, Qw, Ktw);
  k_m<<<512, 256, 0, stream>>>(J, Ktw, Mt_f);
  k_cvt<<<512, 256, 0, stream>>>(Mt_f, Mt_b);
  k_out<<<2048, 256, 0, stream>>>(J, Qw, Mt_b, gamma, beta, out);
}